// Round 2
// baseline (547.536 us; speedup 1.0000x reference)
//
#include <hip/hip_runtime.h>
#include <stdint.h>

#define BB 2
#define SS 2048
#define DMODEL 512
#define NH 8
#define DHD 64

typedef __attribute__((ext_vector_type(8))) short bf16x8;
typedef __attribute__((ext_vector_type(4))) short s16x4;
typedef __attribute__((ext_vector_type(4))) float fx4;

__device__ __forceinline__ short f2bf(float f) {
    union { float f; uint32_t u; } c; c.f = f;
    uint32_t u = c.u;
    u += 0x7fffu + ((u >> 16) & 1u);   // RNE
    return (short)(u >> 16);
}
__device__ __forceinline__ float bf2f(short s) {
    union { uint32_t u; float f; } c; c.u = ((uint32_t)(uint16_t)s) << 16;
    return c.f;
}

// ---------------------------------------------------------------------------
// Fused Q/K/V projection GEMM: z=0 -> qp (bf16 row), z=1 -> kp (bf16 row),
// z=2 -> vt (bf16 TRANSPOSED per batch: vt[(b*512+col)*2048 + s]).
// C = A(4096x512) @ W(512x512) + bias. 64x64 tile, 4 waves, 2x2 MFMA quadrant.
// ---------------------------------------------------------------------------
__global__ __launch_bounds__(256, 4) void qkv_gemm_k(
    const float* __restrict__ q, const float* __restrict__ Wq, const float* __restrict__ bq,
    const float* __restrict__ k, const float* __restrict__ Wk, const float* __restrict__ bk,
    const float* __restrict__ v, const float* __restrict__ Wv, const float* __restrict__ bv,
    short* __restrict__ qp, short* __restrict__ kp, short* __restrict__ vt)
{
    __shared__ short As[64 * 40];   // [m][k] k-contig, pad 40
    __shared__ short Bs[64 * 40];   // [n][k] (W transposed), pad 40
    const int tid = threadIdx.x;
    const int w = tid >> 6, lane = tid & 63;
    const int cl = lane & 15, quad = lane >> 4;
    const int mi = w >> 1, ni = w & 1;
    const int m0 = blockIdx.x * 64, n0 = blockIdx.y * 64;
    const int z = blockIdx.z;
    const float* Af   = (z == 0) ? q  : (z == 1) ? k  : v;
    const float* W    = (z == 0) ? Wq : (z == 1) ? Wk : Wv;
    const float* bias = (z == 0) ? bq : (z == 1) ? bk : bv;
    fx4 acc[2][2] = {};

    for (int k0 = 0; k0 < DMODEL; k0 += 32) {
#pragma unroll
        for (int it = 0; it < 2; ++it) {
            int idx = tid + it * 256;
            int row = idx >> 3, kq = (idx & 7) * 4;
            const float4 vv = *(const float4*)&Af[(size_t)(m0 + row) * DMODEL + k0 + kq];
            s16x4 sv;
            sv.x = f2bf(vv.x); sv.y = f2bf(vv.y); sv.z = f2bf(vv.z); sv.w = f2bf(vv.w);
            *(s16x4*)&As[row * 40 + kq] = sv;
        }
#pragma unroll
        for (int it = 0; it < 2; ++it) {
            int idx = tid + it * 256;
            int kk = idx >> 4, nq = (idx & 15) * 4;
            const float4 vv = *(const float4*)&W[(size_t)(k0 + kk) * DMODEL + n0 + nq];
            Bs[(nq + 0) * 40 + kk] = f2bf(vv.x);
            Bs[(nq + 1) * 40 + kk] = f2bf(vv.y);
            Bs[(nq + 2) * 40 + kk] = f2bf(vv.z);
            Bs[(nq + 3) * 40 + kk] = f2bf(vv.w);
        }
        __syncthreads();
        bf16x8 af[2], bfr[2];
#pragma unroll
        for (int i = 0; i < 2; ++i)
            af[i] = *(const bf16x8*)&As[(mi * 32 + i * 16 + cl) * 40 + quad * 8];
#pragma unroll
        for (int j = 0; j < 2; ++j)
            bfr[j] = *(const bf16x8*)&Bs[(ni * 32 + j * 16 + cl) * 40 + quad * 8];
#pragma unroll
        for (int i = 0; i < 2; ++i)
#pragma unroll
            for (int j = 0; j < 2; ++j)
                acc[i][j] = __builtin_amdgcn_mfma_f32_16x16x32_bf16(af[i], bfr[j], acc[i][j], 0, 0, 0);
        __syncthreads();
    }
    short* Cp = (z == 0) ? qp : (z == 1) ? kp : vt;
    // C/D layout: col=lane&15, row=quad*4+reg
#pragma unroll
    for (int i = 0; i < 2; ++i) {
#pragma unroll
        for (int j = 0; j < 2; ++j) {
            int col = n0 + ni * 32 + j * 16 + cl;
            float bv4 = bias[col];
            int rowbase = m0 + mi * 32 + i * 16 + quad * 4;
            if (z < 2) {
#pragma unroll
                for (int r = 0; r < 4; ++r)
                    Cp[(size_t)(rowbase + r) * DMODEL + col] = f2bf(acc[i][j][r] + bv4);
            } else {
                // transposed per batch: vt[(b*512 + col)*2048 + s], s=row&2047
                int b = rowbase >> 11, s0 = rowbase & 2047;
                s16x4 o;
                o.x = f2bf(acc[i][j][0] + bv4);
                o.y = f2bf(acc[i][j][1] + bv4);
                o.z = f2bf(acc[i][j][2] + bv4);
                o.w = f2bf(acc[i][j][3] + bv4);
                *(s16x4*)&Cp[((size_t)b * DMODEL + col) * SS + s0] = o;
            }
        }
    }
}

// ---------------------------------------------------------------------------
// Final GEMM: out = ao(bf16) @ Wo + bo (fp32 out)
// ---------------------------------------------------------------------------
__global__ __launch_bounds__(256, 4) void out_gemm_k(
    const short* __restrict__ Ab, const float* __restrict__ W,
    const float* __restrict__ bias, float* __restrict__ Cp)
{
    __shared__ short As[64 * 40];
    __shared__ short Bs[64 * 40];
    const int tid = threadIdx.x;
    const int w = tid >> 6, lane = tid & 63;
    const int cl = lane & 15, quad = lane >> 4;
    const int mi = w >> 1, ni = w & 1;
    const int m0 = blockIdx.x * 64, n0 = blockIdx.y * 64;
    fx4 acc[2][2] = {};

    for (int k0 = 0; k0 < DMODEL; k0 += 32) {
#pragma unroll
        for (int it = 0; it < 2; ++it) {
            int idx = tid + it * 256;
            int row = idx >> 3, kq = (idx & 7) * 4;
            *(s16x4*)&As[row * 40 + kq] =
                *(const s16x4*)&Ab[(size_t)(m0 + row) * DMODEL + k0 + kq];
        }
#pragma unroll
        for (int it = 0; it < 2; ++it) {
            int idx = tid + it * 256;
            int kk = idx >> 4, nq = (idx & 15) * 4;
            const float4 vv = *(const float4*)&W[(size_t)(k0 + kk) * DMODEL + n0 + nq];
            Bs[(nq + 0) * 40 + kk] = f2bf(vv.x);
            Bs[(nq + 1) * 40 + kk] = f2bf(vv.y);
            Bs[(nq + 2) * 40 + kk] = f2bf(vv.z);
            Bs[(nq + 3) * 40 + kk] = f2bf(vv.w);
        }
        __syncthreads();
        bf16x8 af[2], bfr[2];
#pragma unroll
        for (int i = 0; i < 2; ++i)
            af[i] = *(const bf16x8*)&As[(mi * 32 + i * 16 + cl) * 40 + quad * 8];
#pragma unroll
        for (int j = 0; j < 2; ++j)
            bfr[j] = *(const bf16x8*)&Bs[(ni * 32 + j * 16 + cl) * 40 + quad * 8];
#pragma unroll
        for (int i = 0; i < 2; ++i)
#pragma unroll
            for (int j = 0; j < 2; ++j)
                acc[i][j] = __builtin_amdgcn_mfma_f32_16x16x32_bf16(af[i], bfr[j], acc[i][j], 0, 0, 0);
        __syncthreads();
    }
#pragma unroll
    for (int i = 0; i < 2; ++i)
#pragma unroll
        for (int j = 0; j < 2; ++j) {
            int col = n0 + ni * 32 + j * 16 + cl;
            float bv4 = bias[col];
#pragma unroll
            for (int r = 0; r < 4; ++r) {
                int row = m0 + mi * 32 + i * 16 + quad * 4 + r;
                Cp[(size_t)row * DMODEL + col] = acc[i][j][r] + bv4;
            }
        }
}

// ---------------------------------------------------------------------------
// a/b head projections (one wave per row)
// ---------------------------------------------------------------------------
__global__ __launch_bounds__(64) void ab_k(
    const short* __restrict__ qp,
    const float* __restrict__ Wa, const float* __restrict__ ba,
    const float* __restrict__ Wb, const float* __restrict__ bbias,
    float* __restrict__ a_ws, float* __restrict__ b_ws)
{
    const int r = blockIdx.x;
    const int lane = threadIdx.x;
    float qv[8];
    s16x4 q0 = *(const s16x4*)&qp[(size_t)r * DMODEL + lane * 8];
    s16x4 q1 = *(const s16x4*)&qp[(size_t)r * DMODEL + lane * 8 + 4];
    qv[0] = bf2f(q0.x); qv[1] = bf2f(q0.y); qv[2] = bf2f(q0.z); qv[3] = bf2f(q0.w);
    qv[4] = bf2f(q1.x); qv[5] = bf2f(q1.y); qv[6] = bf2f(q1.z); qv[7] = bf2f(q1.w);
    float pa[8] = {}, pb[8] = {};
#pragma unroll
    for (int kk = 0; kk < 8; ++kk) {
        int k = lane * 8 + kk;
        const float4 wa0 = *(const float4*)&Wa[k * 8];
        const float4 wa1 = *(const float4*)&Wa[k * 8 + 4];
        const float4 wb0 = *(const float4*)&Wb[k * 8];
        const float4 wb1 = *(const float4*)&Wb[k * 8 + 4];
        float qk = qv[kk];
        pa[0] += qk * wa0.x; pa[1] += qk * wa0.y; pa[2] += qk * wa0.z; pa[3] += qk * wa0.w;
        pa[4] += qk * wa1.x; pa[5] += qk * wa1.y; pa[6] += qk * wa1.z; pa[7] += qk * wa1.w;
        pb[0] += qk * wb0.x; pb[1] += qk * wb0.y; pb[2] += qk * wb0.z; pb[3] += qk * wb0.w;
        pb[4] += qk * wb1.x; pb[5] += qk * wb1.y; pb[6] += qk * wb1.z; pb[7] += qk * wb1.w;
    }
#pragma unroll
    for (int h = 0; h < 8; ++h)
#pragma unroll
        for (int off = 1; off < 64; off <<= 1) {
            pa[h] += __shfl_xor(pa[h], off);
            pb[h] += __shfl_xor(pb[h], off);
        }
    if (lane == 0) {
        int b = r >> 11, s = r & 2047;
#pragma unroll
        for (int h = 0; h < 8; ++h) {
            a_ws[(b * NH + h) * SS + s] = pa[h] + ba[h];
            b_ws[(b * NH + h) * SS + s] = pb[h] + bbias[h];
        }
    }
}

// ---------------------------------------------------------------------------
// Attention: block = (bh, 16-row q tile), 512 threads (8 waves).
// Wave w owns keys [w*256,(w+1)*256). K / V^T fragments read DIRECTLY from
// global (16B loads, L2-resident); LDS only for P round-trip + reductions.
// ---------------------------------------------------------------------------
__global__ __launch_bounds__(512, 4) void attn_k(
    const short* __restrict__ qp, const short* __restrict__ kp, const short* __restrict__ vt,
    const float* __restrict__ a_ws, const float* __restrict__ b_ws,
    const float* __restrict__ xdiff, const int* __restrict__ mask,
    float* __restrict__ attn, short* __restrict__ ao)
{
    __shared__ short ps[8][16 * 72];      // per-wave P staging (A-frag layout)
    __shared__ float ored[4][16 * 68];    // O cross-wave reduce (pad 68: 2-way only)
    __shared__ float redm[128], reds[128], rowa[16], rowb[16];

    const int tid = threadIdx.x;
    const int w = tid >> 6, lane = tid & 63;
    const int cl = lane & 15, quad = lane >> 4;
    const int bh = blockIdx.x;
    const int b = bh >> 3, h = bh & 7;
    const int q0 = blockIdx.y * 16;
    const int bS = b * SS;

    if (tid < 16) {
        rowa[tid] = a_ws[bh * SS + q0 + tid];
        rowb[tid] = b_ws[bh * SS + q0 + tid];
    }
    __syncthreads();

    // Q A-frags direct from global: A[m=cl][k=kc*32+quad*8..]
    const short* qbase = qp + (size_t)(bS + q0 + cl) * DMODEL + h * DHD + quad * 8;
    bf16x8 qf[2];
    qf[0] = *(const bf16x8*)(qbase);
    qf[1] = *(const bf16x8*)(qbase + 32);

    float ra[4], rb[4];
#pragma unroll
    for (int r = 0; r < 4; ++r) { ra[r] = rowa[quad * 4 + r]; rb[r] = rowb[quad * 4 + r]; }

    const int j0w = w * 256;
    fx4 s[4][4];
    float rmax[4] = {-3e38f, -3e38f, -3e38f, -3e38f};

    // ---- pass 1: QK^T + metric terms, scores in regs ----
#pragma unroll
    for (int t = 0; t < 4; ++t) {
        const int j0 = j0w + t * 64;
        fx4 qk[4] = {};
#pragma unroll
        for (int nb = 0; nb < 4; ++nb) {
            const short* kb = kp + (size_t)(bS + j0 + nb * 16 + cl) * DMODEL + h * DHD + quad * 8;
#pragma unroll
            for (int kc = 0; kc < 2; ++kc) {
                bf16x8 kf = *(const bf16x8*)(kb + kc * 32);
                qk[nb] = __builtin_amdgcn_mfma_f32_16x16x32_bf16(qf[kc], kf, qk[nb], 0, 0, 0);
            }
        }
#pragma unroll
        for (int nb = 0; nb < 4; ++nb) {
            const int j = j0 + nb * 16 + cl;
            const float mv = -1.0e9f * (float)mask[bS + j];
            const float* xrow = xdiff + (size_t)(bS + q0 + quad * 4) * SS + j;
#pragma unroll
            for (int r = 0; r < 4; ++r) {
                const float xd = xrow[(size_t)r * SS];
                float val = qk[nb][r] * 0.125f + mv + ra[r] * xd + rb[r] * (xd * xd);
                s[t][nb][r] = val;
                rmax[r] = fmaxf(rmax[r], val);
            }
        }
    }

    // ---- softmax reduce: 16 lanes per row, then 8 waves via LDS ----
#pragma unroll
    for (int off = 1; off < 16; off <<= 1)
#pragma unroll
        for (int r = 0; r < 4; ++r)
            rmax[r] = fmaxf(rmax[r], __shfl_xor(rmax[r], off));
    if (cl == 0)
#pragma unroll
        for (int r = 0; r < 4; ++r) redm[w * 16 + quad * 4 + r] = rmax[r];
    __syncthreads();
    float gm[4];
#pragma unroll
    for (int r = 0; r < 4; ++r) {
        int i = quad * 4 + r;
        float m01 = fmaxf(redm[i], redm[16 + i]);
        float m23 = fmaxf(redm[32 + i], redm[48 + i]);
        float m45 = fmaxf(redm[64 + i], redm[80 + i]);
        float m67 = fmaxf(redm[96 + i], redm[112 + i]);
        gm[r] = fmaxf(fmaxf(m01, m23), fmaxf(m45, m67));
    }

    float rsum[4] = {};
#pragma unroll
    for (int t = 0; t < 4; ++t)
#pragma unroll
        for (int nb = 0; nb < 4; ++nb)
#pragma unroll
            for (int r = 0; r < 4; ++r) {
                float e = __builtin_amdgcn_exp2f((s[t][nb][r] - gm[r]) * 1.44269504f);
                s[t][nb][r] = e;
                rsum[r] += e;
            }
#pragma unroll
    for (int off = 1; off < 16; off <<= 1)
#pragma unroll
        for (int r = 0; r < 4; ++r)
            rsum[r] += __shfl_xor(rsum[r], off);
    if (cl == 0)
#pragma unroll
        for (int r = 0; r < 4; ++r) reds[w * 16 + quad * 4 + r] = rsum[r];
    __syncthreads();
    float gs[4];
#pragma unroll
    for (int r = 0; r < 4; ++r) {
        int i = quad * 4 + r;
        float s0 = reds[i] + reds[16 + i] + reds[32 + i] + reds[48 + i];
        float s1 = reds[64 + i] + reds[80 + i] + reds[96 + i] + reds[112 + i];
        gs[r] = 1.0f / (s0 + s1);
    }

    // ---- pass 2: normalize, write attn, PV (V^T direct from global) ----
    fx4 oacc[4] = {};
    float* attn_bh = attn + (size_t)bh * SS * SS;
    short* psw = ps[w];
    const short* vtb = vt + ((size_t)b * DMODEL + h * DHD) * SS;
#pragma unroll
    for (int t = 0; t < 4; ++t) {
        const int j0 = j0w + t * 64;
#pragma unroll
        for (int nb = 0; nb < 4; ++nb) {
            const int j = j0 + nb * 16 + cl;
            float* arow = attn_bh + (size_t)(q0 + quad * 4) * SS + j;
#pragma unroll
            for (int r = 0; r < 4; ++r) {
                float p = s[t][nb][r] * gs[r];
                arow[(size_t)r * SS] = p;
                psw[(quad * 4 + r) * 72 + nb * 16 + cl] = f2bf(p);
            }
        }
        bf16x8 pf[2];
        pf[0] = *(const bf16x8*)&psw[cl * 72 + quad * 8];
        pf[1] = *(const bf16x8*)&psw[cl * 72 + 32 + quad * 8];
#pragma unroll
        for (int nb = 0; nb < 4; ++nb) {
            const short* vb = vtb + (size_t)(nb * 16 + cl) * SS + j0 + quad * 8;
#pragma unroll
            for (int kc = 0; kc < 2; ++kc) {
                bf16x8 vf = *(const bf16x8*)(vb + kc * 32);
                oacc[nb] = __builtin_amdgcn_mfma_f32_16x16x32_bf16(pf[kc], vf, oacc[nb], 0, 0, 0);
            }
        }
    }

    // ---- cross-wave O reduction: 8 -> 4 buffers -> final ----
    __syncthreads();
    if (w < 4) {
#pragma unroll
        for (int nb = 0; nb < 4; ++nb)
#pragma unroll
            for (int r = 0; r < 4; ++r)
                ored[w][(quad * 4 + r) * 68 + nb * 16 + cl] = oacc[nb][r];
    }
    __syncthreads();
    if (w >= 4) {
        float* o = ored[w - 4];
#pragma unroll
        for (int nb = 0; nb < 4; ++nb)
#pragma unroll
            for (int r = 0; r < 4; ++r)
                o[(quad * 4 + r) * 68 + nb * 16 + cl] += oacc[nb][r];
    }
    __syncthreads();
    if (tid < 256) {
        int i = tid >> 4, dq = (tid & 15) * 4;
        float sx = 0, sy = 0, sz = 0, sw = 0;
#pragma unroll
        for (int ww = 0; ww < 4; ++ww) {
            const float4 vv = *(const float4*)&ored[ww][i * 68 + dq];
            sx += vv.x; sy += vv.y; sz += vv.z; sw += vv.w;
        }
        s16x4 o;
        o.x = f2bf(sx); o.y = f2bf(sy); o.z = f2bf(sz); o.w = f2bf(sw);
        *(s16x4*)&ao[(size_t)(bS + q0 + i) * DMODEL + h * DHD + dq] = o;
    }
}

// ---------------------------------------------------------------------------
extern "C" void kernel_launch(void* const* d_in, const int* in_sizes, int n_in,
                              void* d_out, int out_size, void* d_ws, size_t ws_size,
                              hipStream_t stream)
{
    (void)in_sizes; (void)n_in; (void)out_size; (void)ws_size;
    const float* q     = (const float*)d_in[0];
    const float* k     = (const float*)d_in[1];
    const float* v     = (const float*)d_in[2];
    const float* xdiff = (const float*)d_in[3];
    const int*   mask  = (const int*)d_in[4];
    const float* Wq = (const float*)d_in[5];
    const float* bq = (const float*)d_in[6];
    const float* Wk = (const float*)d_in[7];
    const float* bk = (const float*)d_in[8];
    const float* Wv = (const float*)d_in[9];
    const float* bv = (const float*)d_in[10];
    const float* Wa = (const float*)d_in[11];
    const float* ba = (const float*)d_in[12];
    const float* Wb = (const float*)d_in[13];
    const float* bb = (const float*)d_in[14];
    const float* Wo = (const float*)d_in[15];
    const float* bo = (const float*)d_in[16];

    char* ws = (char*)d_ws;
    short* qp   = (short*)(ws + 0);          // 4096x512 bf16
    short* kp   = (short*)(ws + 4194304);    // 4096x512 bf16
    short* vt   = (short*)(ws + 8388608);    // per-batch transposed: [b][512][2048] bf16
    float* a_ws = (float*)(ws + 12582912);   // (B,H,S) f32
    float* b_ws = (float*)(ws + 12713984);
    short* ao   = (short*)(ws + 12845056);   // 4096x512 bf16

    float* out  = (float*)d_out;
    float* attn = out + (size_t)BB * SS * DMODEL;

    hipLaunchKernelGGL(qkv_gemm_k, dim3(64, 8, 3), dim3(256), 0, stream,
                       q, Wq, bq, k, Wk, bk, v, Wv, bv, qp, kp, vt);
    hipLaunchKernelGGL(ab_k, dim3(4096), dim3(64), 0, stream, qp, Wa, ba, Wb, bb, a_ws, b_ws);
    hipLaunchKernelGGL(attn_k, dim3(16, 128), dim3(512), 0, stream,
                       qp, kp, vt, a_ws, b_ws, xdiff, mask, attn, ao);
    hipLaunchKernelGGL(out_gemm_k, dim3(64, 8), dim3(256), 0, stream, ao, Wo, bo, out);
}